// Round 3
// baseline (23946.289 us; speedup 1.0000x reference)
//
#include <hip/hip_runtime.h>

typedef __attribute__((ext_vector_type(8))) short bh8;
typedef __attribute__((ext_vector_type(4))) float f32x4;

#define BATCH 16
#define SEQ 2048
#define M_ROWS (BATCH * SEQ)   // 32768
#define KDIM 1024

__device__ __forceinline__ unsigned short f2bf(float f) {
  unsigned u = __float_as_uint(f);
  u = (u + 0x7FFFu + ((u >> 16) & 1u)) >> 16;   // round-to-nearest-even
  return (unsigned short)u;
}
__device__ __forceinline__ float bf2f(unsigned short h) {
  return __uint_as_float(((unsigned)h) << 16);
}

__device__ __forceinline__ f32x4 mfma_bf16(bh8 a, bh8 b, f32x4 c) {
  return __builtin_amdgcn_mfma_f32_16x16x32_bf16(a, b, c, 0, 0, 0);
}

__device__ __forceinline__ void gl2lds16(const void* g, void* l) {
  __builtin_amdgcn_global_load_lds(
      (const __attribute__((address_space(1))) void*)g,
      (__attribute__((address_space(3))) void*)l, 16, 0, 0);
}

__global__ void cvt_bf16_kernel(const float* __restrict__ in,
                                unsigned short* __restrict__ out, int n4) {
  int i = blockIdx.x * blockDim.x + threadIdx.x;
  if (i >= n4) return;
  float4 v = ((const float4*)in)[i];
  ushort4 o;
  o.x = f2bf(v.x); o.y = f2bf(v.y); o.z = f2bf(v.z); o.w = f2bf(v.w);
  ((ushort4*)out)[i] = o;
}

__global__ void fill_ones_kernel(float* __restrict__ p, int n) {
  int i = blockIdx.x * blockDim.x + threadIdx.x;
  if (i < n) p[i] = 1.0f;
}

// C[M,N] = A[M,K] * B[N,K]^T   (A,B bf16 row-major, K = 1024)
// MODE 0: fp32 out + bias.  MODE 2: bf16 out, gi-permuted layout [s][wg][g][b][dd].
template<int MODE>
__global__ __launch_bounds__(256, 2) void gemm_nt(
    const unsigned short* __restrict__ A,
    const unsigned short* __restrict__ Bm,
    void* __restrict__ Cout,
    const float* __restrict__ bias,
    int N)
{
  __shared__ unsigned short As[128 * 32];
  __shared__ unsigned short Bs[128 * 32];
  const int tid = threadIdx.x;
  const int wave = tid >> 6, lane = tid & 63;
  const long tileM = (long)blockIdx.y * 128;
  const long tileN = (long)blockIdx.x * 128;

  const int srow = wave * 16 + (lane >> 2);
  const int scol = (lane & 3) * 8;
  const unsigned short* ga = A + (tileM + srow) * KDIM + scol;
  const unsigned short* gb = Bm + (tileN + srow) * KDIM + scol;
  unsigned short* la = As + wave * 512;
  unsigned short* lb = Bs + wave * 512;

  f32x4 acc[4][4];
  #pragma unroll
  for (int i = 0; i < 4; ++i)
    #pragma unroll
    for (int j = 0; j < 4; ++j)
      acc[i][j] = (f32x4){0.f, 0.f, 0.f, 0.f};

  const int wm = wave >> 1, wn = wave & 1;
  const int q = lane >> 4, mr = lane & 15;

  #pragma unroll 1
  for (int kt = 0; kt < 32; ++kt) {
    const int ko = kt * 32;
    gl2lds16(ga + ko, la);
    gl2lds16(ga + (long)64 * KDIM + ko, la + 2048);
    gl2lds16(gb + ko, lb);
    gl2lds16(gb + (long)64 * KDIM + ko, lb + 2048);
    __syncthreads();

    bh8 af[4], bfv[4];
    #pragma unroll
    for (int t = 0; t < 4; ++t)
      af[t] = *(const bh8*)&As[(wm * 64 + t * 16 + mr) * 32 + q * 8];
    #pragma unroll
    for (int t = 0; t < 4; ++t)
      bfv[t] = *(const bh8*)&Bs[(wn * 64 + t * 16 + mr) * 32 + q * 8];

    #pragma unroll
    for (int mt = 0; mt < 4; ++mt)
      #pragma unroll
      for (int nt = 0; nt < 4; ++nt)
        acc[mt][nt] = mfma_bf16(af[mt], bfv[nt], acc[mt][nt]);
    __syncthreads();
  }

  // C/D layout: col = lane&15, row = (lane>>4)*4 + reg
  #pragma unroll
  for (int mt = 0; mt < 4; ++mt) {
    #pragma unroll
    for (int nt = 0; nt < 4; ++nt) {
      long n = tileN + wn * 64 + nt * 16 + mr;
      #pragma unroll
      for (int i = 0; i < 4; ++i) {
        long m = tileM + wm * 64 + mt * 16 + q * 4 + i;
        if constexpr (MODE == 0) {
          ((float*)Cout)[m * N + n] = acc[mt][nt][i] + bias[n];
        } else {
          // permuted: m = b*2048+s ; n = g*1024 + wg*16 + dd
          int b = (int)(m >> 11), s = (int)(m & 2047);
          int g = (int)(n >> 10), wgi = (int)((n >> 4) & 63), dd = (int)(n & 15);
          size_t idx = ((size_t)s * 64 + wgi) * 768 + (size_t)g * 256 + b * 16 + dd;
          ((unsigned short*)Cout)[idx] = f2bf(acc[mt][nt][i]);
        }
      }
    }
  }
}

// Persistent GRU, 64 WGs x 256 threads. h exchange via LLC: each h element is a
// 4-byte word (tag<<16)|bf16, stored/loaded with RELAXED agent-scope atomics
// (sc0 sc1 -> write-through/bypass L2; NO wbl2/inv cache maintenance).
// Readers poll the data itself until all 64 tags == s. 2-buffer ping-pong.
#define GRU_WGS 64
__global__ __launch_bounds__(256, 1) void gru_kernel(
    const unsigned short* __restrict__ gi,   // permuted [s][wg][g][b][dd] bf16
    const unsigned short* __restrict__ whh,  // [3072][1024] bf16
    const float* __restrict__ b_ih,
    const float* __restrict__ b_hh,
    unsigned* __restrict__ hdw,              // [2][16][1024] dwords (tag|bf16), buf0 zeroed
    unsigned short* __restrict__ rnn,        // [M_ROWS][1024] bf16
    float* __restrict__ hidden_out)          // [16][1024] fp32
{
  const int wg = blockIdx.x;
  const int tid = threadIdx.x;
  const int wv = tid >> 6, lane = tid & 63;
  const int D0 = wg * 16;
  const int q = lane >> 4, nn = lane & 15;

  // persistent B-frags: B[k=q*8+j][n=nn] from w_hh rows (g*1024 + D0 + nn)
  bh8 wf[3][8];
  #pragma unroll
  for (int g = 0; g < 3; ++g)
    #pragma unroll
    for (int kk = 0; kk < 8; ++kk) {
      int k = wv * 256 + kk * 32 + q * 8;
      wf[g][kk] = *(const bh8*)&whh[(size_t)(g * 1024 + D0 + nn) * 1024 + k];
    }

  const int b = tid >> 4, dd = tid & 15, d = D0 + dd;
  const float bir = b_ih[d], biz = b_ih[1024 + d], bin_ = b_ih[2048 + d];
  const float bhr = b_hh[d], bhz = b_hh[1024 + d], bhn = b_hh[2048 + d];
  float hreg = 0.0f;

  __shared__ float red[4][3][16][16];   // 12 KB

  #pragma unroll 1
  for (int s = 0; s < SEQ; ++s) {
    // gi prefetch (plain cached loads, contiguous 1.5KB/WG block, off critical path)
    const unsigned short* gbase = gi + ((size_t)s * 64 + wg) * 768 + b * 16 + dd;
    float gir = bf2f(gbase[0]);
    float giz = bf2f(gbase[256]);
    float gin = bf2f(gbase[512]);

    // poll h(s) from LLC: all 64 dwords must carry tag s
    const unsigned* hrow = hdw + (s & 1) * 16384 + nn * 1024 + wv * 256 + q * 8;
    unsigned t[64];
    const unsigned tgtw = (unsigned)s << 16;
    for (;;) {
      #pragma unroll
      for (int kk = 0; kk < 8; ++kk)
        #pragma unroll
        for (int e = 0; e < 8; ++e)
          t[kk * 8 + e] = __hip_atomic_load(&hrow[kk * 32 + e], __ATOMIC_RELAXED,
                                            __HIP_MEMORY_SCOPE_AGENT);
      unsigned bad = 0;
      #pragma unroll
      for (int i = 0; i < 64; ++i) bad |= (t[i] ^ tgtw);
      if ((bad & 0xffff0000u) == 0u) break;
    }

    // pack low-16s into bf16 A-frags and accumulate
    f32x4 acc0 = {0.f,0.f,0.f,0.f}, acc1 = {0.f,0.f,0.f,0.f}, acc2 = {0.f,0.f,0.f,0.f};
    #pragma unroll
    for (int kk = 0; kk < 8; ++kk) {
      union { unsigned w[4]; bh8 v; } u;
      u.w[0] = __builtin_amdgcn_perm(t[kk*8+1], t[kk*8+0], 0x05040100u);
      u.w[1] = __builtin_amdgcn_perm(t[kk*8+3], t[kk*8+2], 0x05040100u);
      u.w[2] = __builtin_amdgcn_perm(t[kk*8+5], t[kk*8+4], 0x05040100u);
      u.w[3] = __builtin_amdgcn_perm(t[kk*8+7], t[kk*8+6], 0x05040100u);
      acc0 = mfma_bf16(u.v, wf[0][kk], acc0);
      acc1 = mfma_bf16(u.v, wf[1][kk], acc1);
      acc2 = mfma_bf16(u.v, wf[2][kk], acc2);
    }
    #pragma unroll
    for (int i = 0; i < 4; ++i) {   // C: row=q*4+i (batch), col=nn (dim)
      red[wv][0][q * 4 + i][nn] = acc0[i];
      red[wv][1][q * 4 + i][nn] = acc1[i];
      red[wv][2][q * 4 + i][nn] = acc2[i];
    }
    __syncthreads();

    float ghr = red[0][0][b][dd] + red[1][0][b][dd] + red[2][0][b][dd] + red[3][0][b][dd];
    float ghz = red[0][1][b][dd] + red[1][1][b][dd] + red[2][1][b][dd] + red[3][1][b][dd];
    float ghn = red[0][2][b][dd] + red[1][2][b][dd] + red[2][2][b][dd] + red[3][2][b][dd];

    float xr = gir + bir + ghr + bhr;
    float xz = giz + biz + ghz + bhz;
    float r = 1.0f / (1.0f + __expf(-xr));
    float z = 1.0f / (1.0f + __expf(-xz));
    float u_ = gin + bin_ + r * (ghn + bhn);
    float e = __expf(-2.0f * fabsf(u_));
    float tt = (1.0f - e) / (1.0f + e);
    float nv = copysignf(tt, u_);
    hreg = (1.0f - z) * nv + z * hreg;

    unsigned short hb = f2bf(hreg);
    // publish h(s+1): value+tag in one dword, relaxed agent store (straight to LLC)
    __hip_atomic_store(&hdw[((s + 1) & 1) * 16384 + b * 1024 + d],
                       (((unsigned)(s + 1)) << 16) | (unsigned)hb,
                       __ATOMIC_RELAXED, __HIP_MEMORY_SCOPE_AGENT);

    rnn[((size_t)b * SEQ + s) * 1024 + d] = hb;   // plain cached store
    if (s == SEQ - 1) hidden_out[b * 1024 + d] = hreg;

    __syncthreads();   // protect red[] reuse next iteration
  }
}

extern "C" void kernel_launch(void* const* d_in, const int* in_sizes, int n_in,
                              void* d_out, int out_size, void* d_ws, size_t ws_size,
                              hipStream_t stream) {
  const float* x    = (const float*)d_in[0];
  // d_in[1..4] = attn weights — dead: softmax over a size-1 axis is identically 1.
  const float* w_ih = (const float*)d_in[5];
  const float* w_hh = (const float*)d_in[6];
  const float* b_ih = (const float*)d_in[7];
  const float* b_hh = (const float*)d_in[8];
  const float* fc_w = (const float*)d_in[9];
  const float* fc_b = (const float*)d_in[10];

  float* out        = (float*)d_out;                       // [16,2048,1024]
  float* hidden_out = out + (size_t)M_ROWS * 1024;         // [1,16,1024]
  float* attn_out   = hidden_out + 16 * 1024;              // [16,2048,1]

  char* ws = (char*)d_ws;
  unsigned short* x_bf   = (unsigned short*)(ws);                 // 67,108,864 B
  unsigned short* wih_bf = (unsigned short*)(ws + 67108864);      //  6,291,456
  unsigned short* whh_bf = (unsigned short*)(ws + 73400320);      //  6,291,456
  unsigned short* fcw_bf = (unsigned short*)(ws + 79691776);      //  2,097,152
  unsigned short* gi_bf  = (unsigned short*)(ws + 81788928);      // 201,326,592
  unsigned short* rnn_bf = (unsigned short*)(ws + 283115520);     // 67,108,864
  unsigned*       hdw    = (unsigned*)(ws + 350224384);           //    131,072

  hipMemsetAsync(hdw, 0, 131072, stream);   // buf0: h(0)=0 tag 0; buf1: tag 0 (!= 1)

  cvt_bf16_kernel<<<32768, 256, 0, stream>>>(x, x_bf, 8388608);
  cvt_bf16_kernel<<<3072, 256, 0, stream>>>(w_ih, wih_bf, 786432);
  cvt_bf16_kernel<<<3072, 256, 0, stream>>>(w_hh, whh_bf, 786432);
  cvt_bf16_kernel<<<1024, 256, 0, stream>>>(fc_w, fcw_bf, 262144);
  fill_ones_kernel<<<128, 256, 0, stream>>>(attn_out, 32768);

  // gi = x @ w_ih^T (bias deferred), bf16, permuted [s][wg][g][b][dd]
  gemm_nt<2><<<dim3(24, 256), 256, 0, stream>>>(x_bf, wih_bf, gi_bf, nullptr, 3072);

  gru_kernel<<<GRU_WGS, 256, 0, stream>>>(gi_bf, whh_bf, b_ih, b_hh, hdw, rnn_bf,
                                          hidden_out);

  // output = rnn @ fc_w^T + fc_b, fp32 out
  gemm_nt<0><<<dim3(8, 256), 256, 0, stream>>>(rnn_bf, fcw_bf, out, fc_b, 1024);
}

// Round 4
// 11003.128 us; speedup vs baseline: 2.1763x; 2.1763x over previous
//
#include <hip/hip_runtime.h>

typedef __attribute__((ext_vector_type(8))) short bh8;
typedef __attribute__((ext_vector_type(4))) float f32x4;

#define BATCH 16
#define SEQ 2048
#define M_ROWS (BATCH * SEQ)   // 32768
#define KDIM 1024

__device__ __forceinline__ unsigned short f2bf(float f) {
  unsigned u = __float_as_uint(f);
  u = (u + 0x7FFFu + ((u >> 16) & 1u)) >> 16;   // round-to-nearest-even
  return (unsigned short)u;
}
__device__ __forceinline__ float bf2f(unsigned short h) {
  return __uint_as_float(((unsigned)h) << 16);
}

__device__ __forceinline__ f32x4 mfma_bf16(bh8 a, bh8 b, f32x4 c) {
  return __builtin_amdgcn_mfma_f32_16x16x32_bf16(a, b, c, 0, 0, 0);
}

__device__ __forceinline__ void gl2lds16(const void* g, void* l) {
  __builtin_amdgcn_global_load_lds(
      (const __attribute__((address_space(1))) void*)g,
      (__attribute__((address_space(3))) void*)l, 16, 0, 0);
}

__global__ void cvt_bf16_kernel(const float* __restrict__ in,
                                unsigned short* __restrict__ out, int n4) {
  int i = blockIdx.x * blockDim.x + threadIdx.x;
  if (i >= n4) return;
  float4 v = ((const float4*)in)[i];
  ushort4 o;
  o.x = f2bf(v.x); o.y = f2bf(v.y); o.z = f2bf(v.z); o.w = f2bf(v.w);
  ((ushort4*)out)[i] = o;
}

__global__ void fill_ones_kernel(float* __restrict__ p, int n) {
  int i = blockIdx.x * blockDim.x + threadIdx.x;
  if (i < n) p[i] = 1.0f;
}

// C[M,N] = A[M,K] * B[N,K]^T   (A,B bf16 row-major, K = 1024)
// MODE 0: fp32 out + bias.  MODE 2: bf16 out, gi-permuted layout [s][wg][g][b][dd].
template<int MODE>
__global__ __launch_bounds__(256, 2) void gemm_nt(
    const unsigned short* __restrict__ A,
    const unsigned short* __restrict__ Bm,
    void* __restrict__ Cout,
    const float* __restrict__ bias,
    int N)
{
  __shared__ unsigned short As[128 * 32];
  __shared__ unsigned short Bs[128 * 32];
  const int tid = threadIdx.x;
  const int wave = tid >> 6, lane = tid & 63;
  const long tileM = (long)blockIdx.y * 128;
  const long tileN = (long)blockIdx.x * 128;

  const int srow = wave * 16 + (lane >> 2);
  const int scol = (lane & 3) * 8;
  const unsigned short* ga = A + (tileM + srow) * KDIM + scol;
  const unsigned short* gb = Bm + (tileN + srow) * KDIM + scol;
  unsigned short* la = As + wave * 512;
  unsigned short* lb = Bs + wave * 512;

  f32x4 acc[4][4];
  #pragma unroll
  for (int i = 0; i < 4; ++i)
    #pragma unroll
    for (int j = 0; j < 4; ++j)
      acc[i][j] = (f32x4){0.f, 0.f, 0.f, 0.f};

  const int wm = wave >> 1, wn = wave & 1;
  const int q = lane >> 4, mr = lane & 15;

  #pragma unroll 1
  for (int kt = 0; kt < 32; ++kt) {
    const int ko = kt * 32;
    gl2lds16(ga + ko, la);
    gl2lds16(ga + (long)64 * KDIM + ko, la + 2048);
    gl2lds16(gb + ko, lb);
    gl2lds16(gb + (long)64 * KDIM + ko, lb + 2048);
    __syncthreads();

    bh8 af[4], bfv[4];
    #pragma unroll
    for (int t = 0; t < 4; ++t)
      af[t] = *(const bh8*)&As[(wm * 64 + t * 16 + mr) * 32 + q * 8];
    #pragma unroll
    for (int t = 0; t < 4; ++t)
      bfv[t] = *(const bh8*)&Bs[(wn * 64 + t * 16 + mr) * 32 + q * 8];

    #pragma unroll
    for (int mt = 0; mt < 4; ++mt)
      #pragma unroll
      for (int nt = 0; nt < 4; ++nt)
        acc[mt][nt] = mfma_bf16(af[mt], bfv[nt], acc[mt][nt]);
    __syncthreads();
  }

  // C/D layout: col = lane&15, row = (lane>>4)*4 + reg
  #pragma unroll
  for (int mt = 0; mt < 4; ++mt) {
    #pragma unroll
    for (int nt = 0; nt < 4; ++nt) {
      long n = tileN + wn * 64 + nt * 16 + mr;
      #pragma unroll
      for (int i = 0; i < 4; ++i) {
        long m = tileM + wm * 64 + mt * 16 + q * 4 + i;
        if constexpr (MODE == 0) {
          ((float*)Cout)[m * N + n] = acc[mt][nt][i] + bias[n];
        } else {
          // permuted: m = b*2048+s ; n = g*1024 + wg*16 + dd
          int b = (int)(m >> 11), s = (int)(m & 2047);
          int g = (int)(n >> 10), wgi = (int)((n >> 4) & 63), dd = (int)(n & 15);
          size_t idx = ((size_t)s * 64 + wgi) * 768 + (size_t)g * 256 + b * 16 + dd;
          ((unsigned short*)Cout)[idx] = f2bf(acc[mt][nt][i]);
        }
      }
    }
  }
}

// Persistent GRU, 64 WGs x 256 threads.
// Transport: h as packed bf16-pair dwords, RELAXED agent-scope atomics
//   (sc-bit accesses, NO wbl2/inv fences — the R1/R2 per-step killer).
// Detector: per-WG padded flag (R2-style), wave0 polls 64 flags (1 load/lane),
//   NOT the data (the R3 poll-storm killer).
// gi: plain cached loads (L2 stays valid — no per-step invalidate anymore).
#define GRU_WGS 64
__global__ __launch_bounds__(256, 1) void gru_kernel(
    const unsigned short* __restrict__ gi,   // permuted [s][wg][g][b][dd] bf16
    const unsigned short* __restrict__ whh,  // [3072][1024] bf16
    const float* __restrict__ b_ih,
    const float* __restrict__ b_hh,
    unsigned* __restrict__ hdw,              // [2][8192] dwords = bf16 pairs, buf0 zeroed
    unsigned* __restrict__ flags,            // [64*16] dwords, one flag per 64B line
    unsigned short* __restrict__ rnn,        // [M_ROWS][1024] bf16
    float* __restrict__ hidden_out)          // [16][1024] fp32
{
  const int wg = blockIdx.x;
  const int tid = threadIdx.x;
  const int wv = tid >> 6, lane = tid & 63;
  const int D0 = wg * 16;
  const int q = lane >> 4, nn = lane & 15;

  // persistent B-frags: B[k=q*8+j][n=nn] from w_hh rows (g*1024 + D0 + nn)
  bh8 wf[3][8];
  #pragma unroll
  for (int g = 0; g < 3; ++g)
    #pragma unroll
    for (int kk = 0; kk < 8; ++kk) {
      int k = wv * 256 + kk * 32 + q * 8;
      wf[g][kk] = *(const bh8*)&whh[(size_t)(g * 1024 + D0 + nn) * 1024 + k];
    }

  const int b = tid >> 4, dd = tid & 15, d = D0 + dd;
  const float bir = b_ih[d], biz = b_ih[1024 + d], bin_ = b_ih[2048 + d];
  const float bhr = b_hh[d], bhz = b_hh[1024 + d], bhn = b_hh[2048 + d];
  float hreg = 0.0f;

  __shared__ float red[4][3][16][16];   // 12 KB

  // gi(0) prefetch (plain cached)
  const unsigned short* g0 = gi + (size_t)wg * 768 + b * 16 + dd;
  unsigned short pg0 = g0[0], pg1 = g0[256], pg2 = g0[512];

  #pragma unroll 1
  for (int s = 0; s < SEQ; ++s) {
    float gir = bf2f(pg0), giz = bf2f(pg1), gin = bf2f(pg2);

    // single-pass h(s) gather: 32 relaxed agent dword loads (bypass L1/L2 -> LLC)
    const unsigned* hrow = hdw + (s & 1) * 8192 + nn * 512 + wv * 128 + q * 4;
    unsigned t[32];
    #pragma unroll
    for (int kk = 0; kk < 8; ++kk)
      #pragma unroll
      for (int j = 0; j < 4; ++j)
        t[kk * 4 + j] = __hip_atomic_load(&hrow[kk * 16 + j], __ATOMIC_RELAXED,
                                          __HIP_MEMORY_SCOPE_AGENT);

    f32x4 acc0 = {0.f,0.f,0.f,0.f}, acc1 = {0.f,0.f,0.f,0.f}, acc2 = {0.f,0.f,0.f,0.f};
    #pragma unroll
    for (int kk = 0; kk < 8; ++kk) {
      union { unsigned w[4]; bh8 v; } u;
      u.w[0] = t[kk*4+0]; u.w[1] = t[kk*4+1]; u.w[2] = t[kk*4+2]; u.w[3] = t[kk*4+3];
      acc0 = mfma_bf16(u.v, wf[0][kk], acc0);
      acc1 = mfma_bf16(u.v, wf[1][kk], acc1);
      acc2 = mfma_bf16(u.v, wf[2][kk], acc2);
    }
    #pragma unroll
    for (int i = 0; i < 4; ++i) {   // C: row=q*4+i (batch), col=nn (dim)
      red[wv][0][q * 4 + i][nn] = acc0[i];
      red[wv][1][q * 4 + i][nn] = acc1[i];
      red[wv][2][q * 4 + i][nn] = acc2[i];
    }
    __syncthreads();

    float ghr = red[0][0][b][dd] + red[1][0][b][dd] + red[2][0][b][dd] + red[3][0][b][dd];
    float ghz = red[0][1][b][dd] + red[1][1][b][dd] + red[2][1][b][dd] + red[3][1][b][dd];
    float ghn = red[0][2][b][dd] + red[1][2][b][dd] + red[2][2][b][dd] + red[3][2][b][dd];

    float xr = gir + bir + ghr + bhr;
    float xz = giz + biz + ghz + bhz;
    float r = 1.0f / (1.0f + __expf(-xr));
    float z = 1.0f / (1.0f + __expf(-xz));
    float u_ = gin + bin_ + r * (ghn + bhn);
    float e = __expf(-2.0f * fabsf(u_));
    float tt = (1.0f - e) / (1.0f + e);
    float nv = copysignf(tt, u_);
    hreg = (1.0f - z) * nv + z * hreg;

    unsigned short hb = f2bf(hreg);
    // publish h(s+1): pack bf16 pair (dims d, d^1) into one dword, even-dd lanes store
    unsigned hp = __shfl_xor((unsigned)hb, 1);
    if ((dd & 1) == 0)
      __hip_atomic_store(&hdw[((s + 1) & 1) * 8192 + b * 512 + ((unsigned)d >> 1)],
                         ((unsigned)hb) | (hp << 16),
                         __ATOMIC_RELAXED, __HIP_MEMORY_SCOPE_AGENT);

    rnn[((size_t)b * SEQ + s) * 1024 + d] = hb;   // plain cached store
    if (s == SEQ - 1) hidden_out[b * 1024 + d] = hreg;

    __syncthreads();   // compiler drains vmcnt(0) per-thread before s_barrier

    if (tid == 0)      // arrival: own flag line, relaxed (h already in LLC)
      __hip_atomic_store(&flags[wg * 16], (unsigned)(s + 1), __ATOMIC_RELAXED,
                         __HIP_MEMORY_SCOPE_AGENT);

    // gi(s+1) prefetch overlaps the spin window
    if (s + 1 < SEQ) {
      const unsigned short* gn = gi + ((size_t)(s + 1) * 64 + wg) * 768 + b * 16 + dd;
      pg0 = gn[0]; pg1 = gn[256]; pg2 = gn[512];
    }

    if (tid < 64) {    // wave0: lane-parallel poll, one flag line per lane
      const unsigned tgt = (unsigned)(s + 1);
      unsigned v;
      do {
        v = __hip_atomic_load(&flags[tid * 16], __ATOMIC_RELAXED,
                              __HIP_MEMORY_SCOPE_AGENT);
      } while (__ballot(v >= tgt) != ~0ull);
    }
    __syncthreads();
  }
}

extern "C" void kernel_launch(void* const* d_in, const int* in_sizes, int n_in,
                              void* d_out, int out_size, void* d_ws, size_t ws_size,
                              hipStream_t stream) {
  const float* x    = (const float*)d_in[0];
  // d_in[1..4] = attn weights — dead: softmax over a size-1 axis is identically 1.
  const float* w_ih = (const float*)d_in[5];
  const float* w_hh = (const float*)d_in[6];
  const float* b_ih = (const float*)d_in[7];
  const float* b_hh = (const float*)d_in[8];
  const float* fc_w = (const float*)d_in[9];
  const float* fc_b = (const float*)d_in[10];

  float* out        = (float*)d_out;                       // [16,2048,1024]
  float* hidden_out = out + (size_t)M_ROWS * 1024;         // [1,16,1024]
  float* attn_out   = hidden_out + 16 * 1024;              // [16,2048,1]

  char* ws = (char*)d_ws;
  unsigned short* x_bf   = (unsigned short*)(ws);                 // 67,108,864 B
  unsigned short* wih_bf = (unsigned short*)(ws + 67108864);      //  6,291,456
  unsigned short* whh_bf = (unsigned short*)(ws + 73400320);      //  6,291,456
  unsigned short* fcw_bf = (unsigned short*)(ws + 79691776);      //  2,097,152
  unsigned short* gi_bf  = (unsigned short*)(ws + 81788928);      // 201,326,592
  unsigned short* rnn_bf = (unsigned short*)(ws + 283115520);     // 67,108,864
  unsigned*       hdw    = (unsigned*)(ws + 350224384);           //     65,536
  unsigned*       flags  = (unsigned*)(ws + 350289920);           //      4,096

  hipMemsetAsync(hdw, 0, 65536 + 4096, stream);   // h(0)=0, flags=0

  cvt_bf16_kernel<<<32768, 256, 0, stream>>>(x, x_bf, 8388608);
  cvt_bf16_kernel<<<3072, 256, 0, stream>>>(w_ih, wih_bf, 786432);
  cvt_bf16_kernel<<<3072, 256, 0, stream>>>(w_hh, whh_bf, 786432);
  cvt_bf16_kernel<<<1024, 256, 0, stream>>>(fc_w, fcw_bf, 262144);
  fill_ones_kernel<<<128, 256, 0, stream>>>(attn_out, 32768);

  // gi = x @ w_ih^T (bias deferred), bf16, permuted [s][wg][g][b][dd]
  gemm_nt<2><<<dim3(24, 256), 256, 0, stream>>>(x_bf, wih_bf, gi_bf, nullptr, 3072);

  gru_kernel<<<GRU_WGS, 256, 0, stream>>>(gi_bf, whh_bf, b_ih, b_hh, hdw, flags,
                                          rnn_bf, hidden_out);

  // output = rnn @ fc_w^T + fc_b, fp32 out
  gemm_nt<0><<<dim3(8, 256), 256, 0, stream>>>(rnn_bf, fcw_bf, out, fc_b, 1024);
}